// Round 6
// baseline (298.373 us; speedup 1.0000x reference)
//
#include <hip/hip_runtime.h>
#include <hip/hip_bf16.h>
#include <cstdint>
#include <cstddef>

#define N_TOK 65536
#define DIM 128
#define HID 256
#define NE 32
#define TOPK 2

typedef __bf16 bf16x8 __attribute__((ext_vector_type(8)));
typedef float f32x4 __attribute__((ext_vector_type(4)));
typedef unsigned uint4v __attribute__((ext_vector_type(4)));

__device__ __forceinline__ unsigned short f2bf(float f) {
  unsigned u = __builtin_bit_cast(unsigned, f);
  u += 0x7fffu + ((u >> 16) & 1u);   // round-to-nearest-even
  return (unsigned short)(u >> 16);
}
__device__ __forceinline__ float bf2f(unsigned s) {
  return __builtin_bit_cast(float, s << 16);
}
__device__ __forceinline__ uint2 split2(float f0, float f1) {
  unsigned u0 = __builtin_bit_cast(unsigned, f0);
  unsigned u1 = __builtin_bit_cast(unsigned, f1);
  unsigned hi = (u0 >> 16) | (u1 & 0xffff0000u);
  float r0 = f0 - __builtin_bit_cast(float, u0 & 0xffff0000u);
  float r1 = f1 - __builtin_bit_cast(float, u1 & 0xffff0000u);
  unsigned lo = (__builtin_bit_cast(unsigned, r0) >> 16) |
                (__builtin_bit_cast(unsigned, r1) & 0xffff0000u);
  uint2 ret; ret.x = hi; ret.y = lo;
  return ret;
}

// ---------------- fallback-only: zero out ----------------
__global__ void k_zero_out(float* __restrict__ out) {
  int t = blockIdx.x * 256 + threadIdx.x;
  float4 z = make_float4(0.f, 0.f, 0.f, 0.f);
  float4* o4 = (float4*)out;
  o4[t] = z;
  o4[t + 1048576] = z;
}

// ---------------- convert + transpose weights (K-chunk-tiled) + router weight prep ----------------
// w1t[e]: element (h,d) at (d>>5)*8192 + h*32 + (d&31)
// w2t[e]: element (d,h) at (h>>5)*4096 + d*32 + (h&31)
__global__ void k_weights(const float* __restrict__ W1, const float* __restrict__ W2,
                          const float* __restrict__ Wr,
                          unsigned short* __restrict__ w1t, unsigned short* __restrict__ w2t,
                          double* __restrict__ wrt64, unsigned short* __restrict__ wrb,
                          float* __restrict__ ws32, int* __restrict__ n_suspect) {
  int b = blockIdx.x;
  if (b == 512) {
    if (threadIdx.x == 0) *n_suspect = 0;
#pragma unroll
    for (int j = 0; j < 16; ++j) {    // fp64 Wr^T
      int idx = j * 256 + threadIdx.x;
      int e = idx >> 7, d = idx & 127;
      wrt64[idx] = (double)Wr[d * NE + e];
    }
#pragma unroll
    for (int j = 0; j < 16; ++j) {    // bf16 hi/lo B-fragments
      int idx = j * 256 + threadIdx.x;
      int k = idx >> 5, e = idx & 31;
      float w = Wr[k * NE + e];
      unsigned u = __builtin_bit_cast(unsigned, w);
      unsigned short hs = (unsigned short)(u >> 16);
      float r = w - __builtin_bit_cast(float, u & 0xffff0000u);
      unsigned short ls = (unsigned short)(__builtin_bit_cast(unsigned, r) >> 16);
      int nt = e >> 4, n = e & 15, kc = k >> 5, q = (k >> 3) & 3, jj = k & 7;
      size_t base = ((((size_t)nt * 4 + kc) * 4 + q) * 16 + n) * 8 + jj;
      wrb[base] = hs;
      wrb[8192 + base] = ls;
    }
    return;
  }
  if (b == 0 && threadIdx.x < 96) ws32[threadIdx.x] = 0.f;
  const float* in;
  unsigned short* out;
  int K, r0, c0;
  if (b < 256) {
    int e = b >> 3, tt = b & 7;
    in = W1 + (size_t)e * DIM * HID;   // [d][h] 128x256
    out = w1t + (size_t)e * DIM * HID;
    K = HID;
    r0 = (tt >> 2) * 64; c0 = (tt & 3) * 64;
  } else {
    b -= 256;
    int e = b >> 3, tt = b & 7;
    in = W2 + (size_t)e * HID * DIM;   // [h][d] 256x128
    out = w2t + (size_t)e * HID * DIM;
    K = DIM;
    r0 = (tt >> 1) * 64; c0 = (tt & 1) * 64;
  }
  __shared__ float tile[64][65];
  int t2 = threadIdx.x;
  int r = t2 >> 2, cs = (t2 & 3) * 16;
  const float* src = in + (size_t)(r0 + r) * K + c0 + cs;
#pragma unroll
  for (int j = 0; j < 4; ++j) {
    float4 v = *(const float4*)(src + j * 4);
    tile[r][cs + j * 4 + 0] = v.x;
    tile[r][cs + j * 4 + 1] = v.y;
    tile[r][cs + j * 4 + 2] = v.z;
    tile[r][cs + j * 4 + 3] = v.w;
  }
  __syncthreads();
#pragma unroll
  for (int p = 0; p < 2; ++p) {
    int orow = p * 32 + (t2 >> 3);
    int oc8 = (t2 & 7) * 8;
    int rr = r0 + oc8;
    unsigned pk[4];
#pragma unroll
    for (int q = 0; q < 4; ++q) {
      unsigned lo = f2bf(tile[oc8 + 2 * q][orow]);
      unsigned hi = f2bf(tile[oc8 + 2 * q + 1][orow]);
      pk[q] = lo | (hi << 16);
    }
    uint4 u;
    u.x = pk[0]; u.y = pk[1]; u.z = pk[2]; u.w = pk[3];
    size_t addr = (size_t)(rr >> 5) * (K * 32) + (size_t)(c0 + orow) * 32 + (rr & 31);
    *(uint4*)(out + addr) = u;
  }
}

// ---------------- router: MFMA split-precision logits + top-2 + fused histogram ----------------
__global__ __launch_bounds__(256) void k_router(
    const float* __restrict__ x, const unsigned short* __restrict__ wrb,
    const float* __restrict__ br, int* __restrict__ top_idx, float* __restrict__ top_val,
    int* __restrict__ suspects, int* __restrict__ n_suspect,
    int* __restrict__ counts, float* __restrict__ importance) {
  __shared__ int hc[NE];
  __shared__ float hf[NE];
  int t = threadIdx.x;
  if (t < NE) { hc[t] = 0; hf[t] = 0.f; }
  __syncthreads();
  int w = t >> 6, l = t & 63, quad = l >> 4, l15 = l & 15;
  int tok0 = blockIdx.x * 256 + w * 64;

  bf16x8 bfr[2][2][4];
#pragma unroll
  for (int s = 0; s < 2; ++s)
#pragma unroll
    for (int nt = 0; nt < 2; ++nt)
#pragma unroll
      for (int kc = 0; kc < 4; ++kc)
        bfr[s][nt][kc] = *(const bf16x8*)(wrb + s * 8192 +
                          ((((size_t)nt * 4 + kc) * 4 + quad) * 16 + l15) * 8);

  f32x4 acc[4][2];
#pragma unroll
  for (int a = 0; a < 4; ++a)
#pragma unroll
    for (int b = 0; b < 2; ++b) {
      f32x4 z = {0.f, 0.f, 0.f, 0.f};
      acc[a][b] = z;
    }

#pragma unroll
  for (int mt = 0; mt < 4; ++mt) {
    const float* xp = x + (size_t)(tok0 + mt * 16 + l15) * DIM + quad * 8;
    float4 va[4][2];
#pragma unroll
    for (int kc = 0; kc < 4; ++kc) {
      const float4* p = (const float4*)(xp + kc * 32);
      va[kc][0] = p[0];
      va[kc][1] = p[1];
    }
#pragma unroll
    for (int kc = 0; kc < 4; ++kc) {
      uint2 s0 = split2(va[kc][0].x, va[kc][0].y);
      uint2 s1 = split2(va[kc][0].z, va[kc][0].w);
      uint2 s2 = split2(va[kc][1].x, va[kc][1].y);
      uint2 s3 = split2(va[kc][1].z, va[kc][1].w);
      uint4v hu, lu;
      hu[0] = s0.x; lu[0] = s0.y;
      hu[1] = s1.x; lu[1] = s1.y;
      hu[2] = s2.x; lu[2] = s2.y;
      hu[3] = s3.x; lu[3] = s3.y;
      bf16x8 ahi = __builtin_bit_cast(bf16x8, hu);
      bf16x8 alo = __builtin_bit_cast(bf16x8, lu);
#pragma unroll
      for (int nt = 0; nt < 2; ++nt) {
        acc[mt][nt] = __builtin_amdgcn_mfma_f32_16x16x32_bf16(ahi, bfr[0][nt][kc], acc[mt][nt], 0, 0, 0);
        acc[mt][nt] = __builtin_amdgcn_mfma_f32_16x16x32_bf16(ahi, bfr[1][nt][kc], acc[mt][nt], 0, 0, 0);
        acc[mt][nt] = __builtin_amdgcn_mfma_f32_16x16x32_bf16(alo, bfr[0][nt][kc], acc[mt][nt], 0, 0, 0);
      }
    }
  }

  float brv0 = br[l15], brv1 = br[16 + l15];
  const float NINF = -3.0e38f;
#pragma unroll
  for (int mt = 0; mt < 4; ++mt) {
#pragma unroll
    for (int r = 0; r < 4; ++r) {
      float c0 = acc[mt][0][r] + brv0;
      float c1 = acc[mt][1][r] + brv1;
      float va = (c0 >= c1) ? c0 : c1;
      int ia = (c0 >= c1) ? l15 : 16 + l15;
#pragma unroll
      for (int off = 1; off < 16; off <<= 1) {
        float ov = __shfl_xor(va, off);
        int oi = __shfl_xor(ia, off);
        if (ov > va || (ov == va && oi < ia)) { va = ov; ia = oi; }
      }
      float v1 = va; int i1 = ia;
      float d0 = (i1 == l15) ? NINF : c0;
      float d1 = (i1 == 16 + l15) ? NINF : c1;
      float vb = (d0 >= d1) ? d0 : d1;
      int ib = (d0 >= d1) ? l15 : 16 + l15;
#pragma unroll
      for (int off = 1; off < 16; off <<= 1) {
        float ov = __shfl_xor(vb, off);
        int oi = __shfl_xor(ib, off);
        if (ov > vb || (ov == vb && oi < ib)) { vb = ov; ib = oi; }
      }
      float v2 = vb; int i2 = ib;
      float e0 = (i1 == l15 || i2 == l15) ? NINF : c0;
      float e1 = (i1 == 16 + l15 || i2 == 16 + l15) ? NINF : c1;
      float vc = (e0 >= e1) ? e0 : e1;
#pragma unroll
      for (int off = 1; off < 16; off <<= 1) {
        float ov = __shfl_xor(vc, off);
        vc = (ov > vc) ? ov : vc;
      }
      float s = __expf(c0 - v1) + __expf(c1 - v1);
#pragma unroll
      for (int off = 1; off < 16; off <<= 1) s += __shfl_xor(s, off);
      if (l15 == 0) {
        int n = tok0 + mt * 16 + quad * 4 + r;
        float g1 = 1.0f / s;
        float g2 = __expf(v2 - v1) / s;
        int2 ti; ti.x = i1; ti.y = i2;
        float2 tv; tv.x = g1; tv.y = g2;
        ((int2*)top_idx)[n] = ti;
        ((float2*)top_val)[n] = tv;
        atomicAdd(&hc[i1], 1);
        atomicAdd(&hc[i2], 1);
        atomicAdd(&hf[i1], g1);
        atomicAdd(&hf[i2], g2);
        if (v2 - vc < 2e-3f) {
          int sidx = atomicAdd(n_suspect, 1);
          suspects[sidx] = n;
        }
      }
    }
  }
  __syncthreads();
  if (t < NE) {
    atomicAdd(&counts[t], hc[t]);
    atomicAdd(&importance[t], hf[t]);
  }
}

// ---------------- fp64 re-resolution of near-tie tokens (+ hist deltas) ----------------
__global__ __launch_bounds__(256) void k_router_fix(
    const float* __restrict__ x, const double* __restrict__ wrt64,
    const float* __restrict__ br, const int* __restrict__ suspects,
    const int* __restrict__ n_suspect, int* __restrict__ top_idx,
    float* __restrict__ top_val, int* __restrict__ counts,
    float* __restrict__ importance) {
  int t = threadIdx.x;
  int lt = t & 31;
  int gid = blockIdx.x * 8 + (t >> 5);
  int cnt = *n_suspect;
  const double* wcol = wrt64 + lt * DIM;
  for (int s = gid; s < cnt; s += 128 * 8) {
    int n = suspects[s];
    const float* xr = x + (size_t)n * DIM;
    double a = 0.0;
#pragma unroll 8
    for (int d = 0; d < DIM; ++d) a = fma((double)xr[d], wcol[d], a);
    double lv = a + (double)br[lt];

    double v1 = lv; int i1 = lt;
#pragma unroll
    for (int off = 16; off > 0; off >>= 1) {
      double ov = __shfl_xor(v1, off, 32);
      int oi = __shfl_xor(i1, off, 32);
      if (ov > v1 || (ov == v1 && oi < i1)) { v1 = ov; i1 = oi; }
    }
    double lv2 = (lt == i1) ? -1.0e300 : lv;
    double v2 = lv2; int i2 = lt;
#pragma unroll
    for (int off = 16; off > 0; off >>= 1) {
      double ov = __shfl_xor(v2, off, 32);
      int oi = __shfl_xor(i2, off, 32);
      if (ov > v2 || (ov == v2 && oi < i2)) { v2 = ov; i2 = oi; }
    }
    float p = expf((float)(lv - v1));
    float ssum = p;
#pragma unroll
    for (int off = 16; off > 0; off >>= 1) ssum += __shfl_xor(ssum, off, 32);
    if (lt == 0) {
      int i1o = top_idx[n * 2 + 0], i2o = top_idx[n * 2 + 1];
      float g1o = top_val[n * 2 + 0], g2o = top_val[n * 2 + 1];
      float g1 = 1.0f / ssum;
      float g2 = expf((float)(v2 - v1)) / ssum;
      top_idx[n * 2 + 0] = i1;
      top_idx[n * 2 + 1] = i2;
      top_val[n * 2 + 0] = g1;
      top_val[n * 2 + 1] = g2;
      atomicAdd(&counts[i1o], -1); atomicAdd(&counts[i2o], -1);
      atomicAdd(&counts[i1], 1);   atomicAdd(&counts[i2], 1);
      atomicAdd(&importance[i1o], -g1o); atomicAdd(&importance[i2o], -g2o);
      atomicAdd(&importance[i1], g1);    atomicAdd(&importance[i2], g2);
    }
  }
}

// ---------------- fallback-only: fp64 router ----------------
__global__ __launch_bounds__(256) void k_router_f64(const float* __restrict__ x,
                                                    const double* __restrict__ wrt64,
                                                    const float* __restrict__ br,
                                                    int* __restrict__ top_idx,
                                                    float* __restrict__ top_val) {
  int t = threadIdx.x;
  int lt = t & 31;
  int n = blockIdx.x * 8 + (t >> 5);
  const double* wcol = wrt64 + lt * DIM;
  const float* xr = x + (size_t)n * DIM;
  double a = 0.0;
#pragma unroll 8
  for (int d = 0; d < DIM; ++d) a = fma((double)xr[d], wcol[d], a);
  double lv = a + (double)br[lt];
  double v1 = lv; int i1 = lt;
#pragma unroll
  for (int off = 16; off > 0; off >>= 1) {
    double ov = __shfl_xor(v1, off, 32);
    int oi = __shfl_xor(i1, off, 32);
    if (ov > v1 || (ov == v1 && oi < i1)) { v1 = ov; i1 = oi; }
  }
  double lv2 = (lt == i1) ? -1.0e300 : lv;
  double v2 = lv2; int i2 = lt;
#pragma unroll
  for (int off = 16; off > 0; off >>= 1) {
    double ov = __shfl_xor(v2, off, 32);
    int oi = __shfl_xor(i2, off, 32);
    if (ov > v2 || (ov == v2 && oi < i2)) { v2 = ov; i2 = oi; }
  }
  float p = expf((float)(lv - v1));
  float ssum = p;
#pragma unroll
  for (int off = 16; off > 0; off >>= 1) ssum += __shfl_xor(ssum, off, 32);
  if (lt == 0) {
    top_idx[n * 2 + 0] = i1;
    top_idx[n * 2 + 1] = i2;
    top_val[n * 2 + 0] = 1.0f / ssum;
    top_val[n * 2 + 1] = expf((float)(v2 - v1)) / ssum;
  }
}

// ---------------- fallback-only: histogram ----------------
__global__ void k_hist(const int* __restrict__ top_idx, const float* __restrict__ top_val,
                       int* __restrict__ counts, float* __restrict__ importance) {
  __shared__ int hc[NE];
  __shared__ float hf[NE];
  int t = threadIdx.x;
  if (t < NE) { hc[t] = 0; hf[t] = 0.f; }
  __syncthreads();
#pragma unroll
  for (int j = 0; j < 2; ++j) {
    int i = (j * 256 + blockIdx.x) * 256 + t;
    int e = top_idx[i];
    atomicAdd(&hc[e], 1);
    atomicAdd(&hf[e], top_val[i]);
  }
  __syncthreads();
  if (t < NE) {
    atomicAdd(&counts[t], hc[t]);
    atomicAdd(&importance[t], hf[t]);
  }
}

// ---------------- scatter (+ in-block scan, block0 computes loss) ----------------
// perm[pos] = token*2 + k  (k = which of the token's two slots)
__global__ void k_scatter(const int* __restrict__ top_idx, const float* __restrict__ top_val,
                          const int* __restrict__ counts, const float* __restrict__ importance,
                          int* __restrict__ cursors, int* __restrict__ perm,
                          float* __restrict__ gatev, float* __restrict__ out_loss) {
  __shared__ int hist[NE], base[NE], cur[NE], off_s[NE];
  int t = threadIdx.x;
  if (t < NE) {
    hist[t] = 0; cur[t] = 0;
    int pc = (counts[t] + 63) & ~63;
    int sc = pc;
#pragma unroll
    for (int off = 1; off < 32; off <<= 1) {
      int ov = __shfl_up(sc, off, 32);
      if (t >= off) sc += ov;
    }
    off_s[t] = sc - pc;
    if (blockIdx.x == 0) {
      float imp = importance[t];
      float ssum = imp;
#pragma unroll
      for (int off = 16; off > 0; off >>= 1) ssum += __shfl_xor(ssum, off, 32);
      float mean = ssum / 32.0f;
      float dlt = imp - mean;
      float v = dlt * dlt;
#pragma unroll
      for (int off = 16; off > 0; off >>= 1) v += __shfl_xor(v, off, 32);
      float var = v / 31.0f;
      if (t == 0) *out_loss = var / (mean * mean + 1e-9f);
    }
  }
  __syncthreads();
#pragma unroll
  for (int j = 0; j < 4; ++j) {
    int i = blockIdx.x * 1024 + j * 256 + t;
    atomicAdd(&hist[top_idx[i]], 1);
  }
  __syncthreads();
  if (t < NE) base[t] = atomicAdd(&cursors[t], hist[t]);
  __syncthreads();
#pragma unroll
  for (int j = 0; j < 4; ++j) {
    int i = blockIdx.x * 1024 + j * 256 + t;
    int e = top_idx[i];
    int p = atomicAdd(&cur[e], 1);
    int pos = off_s[e] + base[e] + p;
    perm[pos] = i;                 // token*2 + k
    gatev[pos] = top_val[i];
  }
}

// ---------------- persistent fused expert GEMM: 16 blocks/expert, chunk loop ----------------
// Weights in VGPRs once per block; x-gather for next chunk prefetched during MFMA.
// YB=1: y -> ybuf[token*2+k][128] (bf16); YB=0: atomicAdd into out (fallback).
template <int YB>
__global__ __launch_bounds__(256, 2) void k_expert(
    const float* __restrict__ x, const unsigned short* __restrict__ w1t,
    const unsigned short* __restrict__ w2t, const float* __restrict__ b1,
    const float* __restrict__ b2, const int* __restrict__ counts,
    const int* __restrict__ perm, const float* __restrict__ gatev,
    unsigned short* __restrict__ ybuf, float* __restrict__ out) {
  __shared__ __align__(16) unsigned char smem[49152];
  unsigned char* xa = smem;                 // 16 KB: [c 0..15][row 0..63][16B]
  unsigned char* ha = smem + 16384;         // 32 KB: [c 0..31][row 0..63][16B]
  __shared__ int off_s[NE];

  int t = threadIdx.x;
  if (t < NE) {
    int pc = (counts[t] + 63) & ~63;
    int sc = pc;
#pragma unroll
    for (int off = 1; off < 32; off <<= 1) {
      int ov = __shfl_up(sc, off, 32);
      if (t >= off) sc += ov;
    }
    off_s[t] = sc - pc;
  }
  __syncthreads();

  int e = blockIdx.x >> 4;
  int sub = blockIdx.x & 15;
  int cnt = counts[e];
  int slotbase = off_s[e];
  int nch = (cnt + 63) >> 6;

  int w = t >> 6, l = t & 63, quad = l >> 4, l15 = l & 15;
  int r = t & 63, half = t >> 6;   // staging role: row r, quarter half

  // ---- weights -> VGPRs (once per block) ----
  const unsigned short* w1e = w1t + (size_t)e * DIM * HID;
  bf16x8 w1f[4][4];
#pragma unroll
  for (int kc = 0; kc < 4; ++kc)
#pragma unroll
    for (int jt = 0; jt < 4; ++jt)
      w1f[kc][jt] = *(const bf16x8*)(w1e + kc * 8192 + (w * 64 + jt * 16 + l15) * 32 + quad * 8);
  const unsigned short* w2e = w2t + (size_t)e * HID * DIM;
  bf16x8 w2f[8][2];
#pragma unroll
  for (int hc = 0; hc < 8; ++hc)
#pragma unroll
    for (int jt = 0; jt < 2; ++jt)
      w2f[hc][jt] = *(const bf16x8*)(w2e + hc * 4096 + (w * 32 + jt * 16 + l15) * 32 + quad * 8);

  // biases (block-constant)
  const float* b1e = b1 + e * HID;
  float b1v[4];
#pragma unroll
  for (int jt = 0; jt < 4; ++jt) b1v[jt] = b1e[w * 64 + jt * 16 + l15];
  int dbase = w * 32;
  float b2v0 = b2[e * DIM + dbase + l15];
  float b2v1 = b2[e * DIM + dbase + 16 + l15];

  // ---- prefetch first chunk into pk ----
  int c = sub;
  unsigned pk[16];
  {
    bool hv = (c < nch) && (r < cnt - c * 64);
    if (hv) {
      int pmv = perm[slotbase + c * 64 + r];
      const float* src = x + (size_t)(pmv >> 1) * DIM + half * 32;
#pragma unroll
      for (int q = 0; q < 8; ++q) {
        float4 v = ((const float4*)src)[q];
        pk[q * 2 + 0] = (unsigned)f2bf(v.x) | ((unsigned)f2bf(v.y) << 16);
        pk[q * 2 + 1] = (unsigned)f2bf(v.z) | ((unsigned)f2bf(v.w) << 16);
      }
    } else {
#pragma unroll
      for (int q = 0; q < 16; ++q) pk[q] = 0u;
    }
  }

  while (c < nch) {
    // ---- write current chunk to xa ----
#pragma unroll
    for (int cc = 0; cc < 4; ++cc) {
      uint4 u;
      u.x = pk[cc * 4 + 0]; u.y = pk[cc * 4 + 1]; u.z = pk[cc * 4 + 2]; u.w = pk[cc * 4 + 3];
      *(uint4*)(xa + (half * 4 + cc) * 1024 + r * 16) = u;
    }
    __syncthreads();

    // ---- issue next chunk's gather (overlaps MFMA below) ----
    int cn = c + 16;
    bool hvn = (cn < nch) && (r < cnt - cn * 64);
    float4 nx[8];
    if (hvn) {
      int pmn = perm[slotbase + cn * 64 + r];
      const float* srcn = x + (size_t)(pmn >> 1) * DIM + half * 32;
#pragma unroll
      for (int q = 0; q < 8; ++q) nx[q] = ((const float4*)srcn)[q];
    }

    // ---- stage 1: H = relu(X @ W1e + b1) ----
    f32x4 acc[4][4];
#pragma unroll
    for (int a = 0; a < 4; ++a)
#pragma unroll
      for (int b = 0; b < 4; ++b) {
        f32x4 z = {0.f, 0.f, 0.f, 0.f};
        acc[a][b] = z;
      }
#pragma unroll
    for (int kc = 0; kc < 4; ++kc) {
      bf16x8 af[4];
#pragma unroll
      for (int rt = 0; rt < 4; ++rt)
        af[rt] = *(const bf16x8*)(xa + (kc * 4 + quad) * 1024 + (rt * 16 + l15) * 16);
#pragma unroll
      for (int rt = 0; rt < 4; ++rt)
#pragma unroll
        for (int jt = 0; jt < 4; ++jt)
          acc[rt][jt] = __builtin_amdgcn_mfma_f32_16x16x32_bf16(af[rt], w1f[kc][jt], acc[rt][jt], 0, 0, 0);
    }

    // ---- bias + relu + H -> LDS (A-layout bf16) ----
#pragma unroll
    for (int jt = 0; jt < 4; ++jt) {
      int col = w * 64 + jt * 16 + l15;
      int cidx = col >> 3;
      int byteoff = (col & 7) * 2;
#pragma unroll
      for (int rt = 0; rt < 4; ++rt) {
#pragma unroll
        for (int rr = 0; rr < 4; ++rr) {
          int tokrow = rt * 16 + quad * 4 + rr;
          float v = acc[rt][jt][rr] + b1v[jt];
          v = v > 0.f ? v : 0.f;
          *(unsigned short*)(ha + cidx * 1024 + tokrow * 16 + byteoff) = f2bf(v);
        }
      }
    }
    __syncthreads();

    // ---- stage 2: O = H @ W2e ----
    f32x4 accc[4][2];
#pragma unroll
    for (int a = 0; a < 4; ++a)
#pragma unroll
      for (int b = 0; b < 2; ++b) {
        f32x4 z = {0.f, 0.f, 0.f, 0.f};
        accc[a][b] = z;
      }
#pragma unroll
    for (int hc = 0; hc < 8; ++hc) {
      bf16x8 ah[4];
#pragma unroll
      for (int rt = 0; rt < 4; ++rt)
        ah[rt] = *(const bf16x8*)(ha + (hc * 4 + quad) * 1024 + (rt * 16 + l15) * 16);
#pragma unroll
      for (int rt = 0; rt < 4; ++rt)
#pragma unroll
        for (int jt = 0; jt < 2; ++jt)
          accc[rt][jt] = __builtin_amdgcn_mfma_f32_16x16x32_bf16(ah[rt], w2f[hc][jt], accc[rt][jt], 0, 0, 0);
    }

    // ---- epilogue: y = g*(O+b2) ----
    int slot0 = slotbase + c * 64;
    int nv = cnt - c * 64; nv = nv > 64 ? 64 : nv;
#pragma unroll
    for (int rt = 0; rt < 4; ++rt) {
#pragma unroll
      for (int rr = 0; rr < 4; ++rr) {
        int tokrow = rt * 16 + quad * 4 + rr;
        if (tokrow < nv) {
          int pos = slot0 + tokrow;
          int pmv = perm[pos];
          float g = gatev[pos];
          if (YB) {
            unsigned short* yrow = ybuf + (size_t)pmv * DIM + dbase;
            yrow[l15] = f2bf(g * (accc[rt][0][rr] + b2v0));
            yrow[16 + l15] = f2bf(g * (accc[rt][1][rr] + b2v1));
          } else {
            float* orow = out + (size_t)(pmv >> 1) * DIM + dbase;
            atomicAdd(&orow[l15], g * (accc[rt][0][rr] + b2v0));
            atomicAdd(&orow[16 + l15], g * (accc[rt][1][rr] + b2v1));
          }
        }
      }
    }

    // ---- convert prefetched chunk ----
    if (hvn) {
#pragma unroll
      for (int q = 0; q < 8; ++q) {
        pk[q * 2 + 0] = (unsigned)f2bf(nx[q].x) | ((unsigned)f2bf(nx[q].y) << 16);
        pk[q * 2 + 1] = (unsigned)f2bf(nx[q].z) | ((unsigned)f2bf(nx[q].w) << 16);
      }
    } else {
#pragma unroll
      for (int q = 0; q < 16; ++q) pk[q] = 0u;
    }
    c = cn;
  }
}

// ---------------- combine: out[n] = ybuf[2n] + ybuf[2n+1] (fully coalesced) ----------------
__global__ __launch_bounds__(256) void k_combine(const unsigned short* __restrict__ ybuf,
                                                 float* __restrict__ out) {
  int t = threadIdx.x;
  int n = blockIdx.x * 16 + (t >> 4);
  int lane = t & 15;
  const uint4* rows = (const uint4*)(ybuf + (size_t)(2 * n) * DIM);
  uint4 a = rows[lane];
  uint4 b = rows[16 + lane];
  unsigned av[4] = {a.x, a.y, a.z, a.w}, bv[4] = {b.x, b.y, b.z, b.w};
  float r[8];
#pragma unroll
  for (int q = 0; q < 4; ++q) {
    r[q * 2 + 0] = bf2f(av[q] & 0xffffu) + bf2f(bv[q] & 0xffffu);
    r[q * 2 + 1] = bf2f(av[q] >> 16) + bf2f(bv[q] >> 16);
  }
  float* orow = out + (size_t)n * DIM + lane * 8;
  float4 w0 = {r[0], r[1], r[2], r[3]}, w1 = {r[4], r[5], r[6], r[7]};
  ((float4*)orow)[0] = w0;
  ((float4*)orow)[1] = w1;
}

extern "C" void kernel_launch(void* const* d_in, const int* in_sizes, int n_in,
                              void* d_out, int out_size, void* d_ws, size_t ws_size,
                              hipStream_t stream) {
  const float* x  = (const float*)d_in[0];
  const float* W1 = (const float*)d_in[1];
  const float* b1 = (const float*)d_in[2];
  const float* W2 = (const float*)d_in[3];
  const float* b2 = (const float*)d_in[4];
  const float* Wr = (const float*)d_in[5];
  const float* br = (const float*)d_in[6];
  float* out = (float*)d_out;

  char* ws = (char*)d_ws;
  float* importance   = (float*)(ws + 0);       // 32 f
  int*   counts       = (int*)(ws + 128);       // 32 i
  int*   cursors      = (int*)(ws + 256);       // 32 i
  int*   top_idx      = (int*)(ws + 1024);              // -> 525312
  float* top_val      = (float*)(ws + 525312);          // -> 1049600
  int*   perm         = (int*)(ws + 1049600);           // 133120 i -> 1582080
  float* gatev        = (float*)(ws + 1582080);         // -> 2114560
  unsigned short* w1t = (unsigned short*)(ws + 2114560);            // 2 MB -> 4211712
  unsigned short* w2t = (unsigned short*)(ws + 4211712);            // 2 MB -> 6308864
  unsigned short* ybuf = (unsigned short*)(ws + 6308864);           // 32 MB -> 39863296
  double* wrt64 = (double*)(ws + 6308864);              // aliases ybuf head (dead before k_expert)
  unsigned short* wrb = (unsigned short*)(ws + 6308864 + 32768);    // aliases ybuf
  int* suspects = (int*)(ws + 39863296);                // -> 40125440
  int* n_suspect = (int*)(ws + 40125440);               // -> 40125568
  const size_t NEEDED = 40125568;
  bool use_ybuf = ws_size >= NEEDED;

  hipLaunchKernelGGL(k_weights, dim3(513), dim3(256), 0, stream, W1, W2, Wr, w1t, w2t, wrt64,
                     wrb, (float*)ws, n_suspect);
  if (use_ybuf) {
    hipLaunchKernelGGL(k_router, dim3(256), dim3(256), 0, stream, x, wrb, br, top_idx, top_val,
                       suspects, n_suspect, counts, importance);
    hipLaunchKernelGGL(k_router_fix, dim3(128), dim3(256), 0, stream, x, wrt64, br, suspects,
                       n_suspect, top_idx, top_val, counts, importance);
  } else {
    hipLaunchKernelGGL(k_router_f64, dim3(8192), dim3(256), 0, stream, x, wrt64, br, top_idx,
                       top_val);
    hipLaunchKernelGGL(k_hist, dim3(256), dim3(256), 0, stream, top_idx, top_val, counts,
                       importance);
  }
  hipLaunchKernelGGL(k_scatter, dim3(128), dim3(256), 0, stream, top_idx, top_val, counts,
                     importance, cursors, perm, gatev, out + (size_t)N_TOK * DIM);
  if (use_ybuf) {
    hipLaunchKernelGGL((k_expert<1>), dim3(512), dim3(256), 0, stream, x, w1t, w2t, b1, b2,
                       counts, perm, gatev, ybuf, out);
    hipLaunchKernelGGL(k_combine, dim3(4096), dim3(256), 0, stream, ybuf, out);
  } else {
    hipLaunchKernelGGL(k_zero_out, dim3(4096), dim3(256), 0, stream, out);
    hipLaunchKernelGGL((k_expert<0>), dim3(512), dim3(256), 0, stream, x, w1t, w2t, b1, b2,
                       counts, perm, gatev, ybuf, out);
  }
}

// Round 7
// 240.677 us; speedup vs baseline: 1.2397x; 1.2397x over previous
//
#include <hip/hip_runtime.h>
#include <hip/hip_bf16.h>
#include <cstdint>
#include <cstddef>

#define N_TOK 65536
#define DIM 128
#define HID 256
#define NE 32
#define TOPK 2

typedef __bf16 bf16x8 __attribute__((ext_vector_type(8)));
typedef float f32x4 __attribute__((ext_vector_type(4)));
typedef unsigned uint4v __attribute__((ext_vector_type(4)));

__device__ __forceinline__ unsigned short f2bf(float f) {
  unsigned u = __builtin_bit_cast(unsigned, f);
  u += 0x7fffu + ((u >> 16) & 1u);   // round-to-nearest-even
  return (unsigned short)(u >> 16);
}
__device__ __forceinline__ float bf2f(unsigned s) {
  return __builtin_bit_cast(float, s << 16);
}
__device__ __forceinline__ uint2 split2(float f0, float f1) {
  unsigned u0 = __builtin_bit_cast(unsigned, f0);
  unsigned u1 = __builtin_bit_cast(unsigned, f1);
  unsigned hi = (u0 >> 16) | (u1 & 0xffff0000u);
  float r0 = f0 - __builtin_bit_cast(float, u0 & 0xffff0000u);
  float r1 = f1 - __builtin_bit_cast(float, u1 & 0xffff0000u);
  unsigned lo = (__builtin_bit_cast(unsigned, r0) >> 16) |
                (__builtin_bit_cast(unsigned, r1) & 0xffff0000u);
  uint2 ret; ret.x = hi; ret.y = lo;
  return ret;
}

// ---------------- fallback-only: zero out ----------------
__global__ void k_zero_out(float* __restrict__ out) {
  int t = blockIdx.x * 256 + threadIdx.x;
  float4 z = make_float4(0.f, 0.f, 0.f, 0.f);
  float4* o4 = (float4*)out;
  o4[t] = z;
  o4[t + 1048576] = z;
}

// ---------------- convert + transpose weights (K-chunk-tiled, column-permuted) ----------------
// w1t[e]: element (h,d) stored at (d>>5)*8192 + hperm(h)*32 + (d&31)
//   hperm(h) = (h&~63) | ((h&3)<<4) | ((h>>2)&15)  => MFMA tile jt holds cols n*4+jt
// w2t[e]: element (d,h) stored at (h>>5)*4096 + dperm(d)*32 + (h&31)
//   dperm(d) = (d&~31) | ((d&1)<<4) | ((d>>1)&15)  => tile jt holds cols n*2+jt
__global__ void k_weights(const float* __restrict__ W1, const float* __restrict__ W2,
                          const float* __restrict__ Wr,
                          unsigned short* __restrict__ w1t, unsigned short* __restrict__ w2t,
                          double* __restrict__ wrt64, unsigned short* __restrict__ wrb,
                          float* __restrict__ ws32, int* __restrict__ n_suspect) {
  int b = blockIdx.x;
  if (b == 512) {
    if (threadIdx.x == 0) *n_suspect = 0;
#pragma unroll
    for (int j = 0; j < 16; ++j) {    // fp64 Wr^T
      int idx = j * 256 + threadIdx.x;
      int e = idx >> 7, d = idx & 127;
      wrt64[idx] = (double)Wr[d * NE + e];
    }
#pragma unroll
    for (int j = 0; j < 16; ++j) {    // bf16 hi/lo B-fragments of Wr
      int idx = j * 256 + threadIdx.x;
      int k = idx >> 5, e = idx & 31;
      float w = Wr[k * NE + e];
      unsigned u = __builtin_bit_cast(unsigned, w);
      unsigned short hs = (unsigned short)(u >> 16);
      float r = w - __builtin_bit_cast(float, u & 0xffff0000u);
      unsigned short ls = (unsigned short)(__builtin_bit_cast(unsigned, r) >> 16);
      int nt = e >> 4, n = e & 15, kc = k >> 5, q = (k >> 3) & 3, jj = k & 7;
      size_t base = ((((size_t)nt * 4 + kc) * 4 + q) * 16 + n) * 8 + jj;
      wrb[base] = hs;
      wrb[8192 + base] = ls;
    }
    return;
  }
  if (b == 0 && threadIdx.x < 96) ws32[threadIdx.x] = 0.f;
  const float* in;
  unsigned short* out;
  int K, r0, c0;
  bool isW1 = (b < 256);
  if (isW1) {
    int e = b >> 3, tt = b & 7;
    in = W1 + (size_t)e * DIM * HID;   // [d][h] 128x256
    out = w1t + (size_t)e * DIM * HID;
    K = HID;
    r0 = (tt >> 2) * 64; c0 = (tt & 3) * 64;
  } else {
    b -= 256;
    int e = b >> 3, tt = b & 7;
    in = W2 + (size_t)e * HID * DIM;   // [h][d] 256x128
    out = w2t + (size_t)e * HID * DIM;
    K = DIM;
    r0 = (tt >> 1) * 64; c0 = (tt & 1) * 64;
  }
  __shared__ float tile[64][65];
  int t2 = threadIdx.x;
  int r = t2 >> 2, cs = (t2 & 3) * 16;
  const float* src = in + (size_t)(r0 + r) * K + c0 + cs;
#pragma unroll
  for (int j = 0; j < 4; ++j) {
    float4 v = *(const float4*)(src + j * 4);
    tile[r][cs + j * 4 + 0] = v.x;
    tile[r][cs + j * 4 + 1] = v.y;
    tile[r][cs + j * 4 + 2] = v.z;
    tile[r][cs + j * 4 + 3] = v.w;
  }
  __syncthreads();
#pragma unroll
  for (int p = 0; p < 2; ++p) {
    int orow = p * 32 + (t2 >> 3);        // col index (h for W1, d for W2)
    int oc8 = (t2 & 7) * 8;
    int rr = r0 + oc8;                    // row index, 8 consecutive
    unsigned pk[4];
#pragma unroll
    for (int q = 0; q < 4; ++q) {
      unsigned lo = f2bf(tile[oc8 + 2 * q][orow]);
      unsigned hi = f2bf(tile[oc8 + 2 * q + 1][orow]);
      pk[q] = lo | (hi << 16);
    }
    uint4 u;
    u.x = pk[0]; u.y = pk[1]; u.z = pk[2]; u.w = pk[3];
    int cc = c0 + orow;
    int cp;
    if (isW1) cp = (cc & ~63) | ((cc & 3) << 4) | ((cc >> 2) & 15);
    else      cp = (cc & ~31) | ((cc & 1) << 4) | ((cc >> 1) & 15);
    size_t addr = (size_t)(rr >> 5) * (K * 32) + (size_t)cp * 32 + (rr & 31);
    *(uint4*)(out + addr) = u;
  }
}

// ---------------- router: MFMA split-precision logits + top-2 + fused histogram ----------------
// 1024 blocks x 64 tokens (16/wave)
__global__ __launch_bounds__(256) void k_router(
    const float* __restrict__ x, const unsigned short* __restrict__ wrb,
    const float* __restrict__ br, int* __restrict__ top_idx, float* __restrict__ top_val,
    int* __restrict__ suspects, int* __restrict__ n_suspect,
    int* __restrict__ counts, float* __restrict__ importance) {
  __shared__ int hc[NE];
  __shared__ float hf[NE];
  int t = threadIdx.x;
  if (t < NE) { hc[t] = 0; hf[t] = 0.f; }
  __syncthreads();
  int w = t >> 6, l = t & 63, quad = l >> 4, l15 = l & 15;
  int tokw = blockIdx.x * 64 + w * 16;

  bf16x8 bfr[2][2][4];
#pragma unroll
  for (int s = 0; s < 2; ++s)
#pragma unroll
    for (int nt = 0; nt < 2; ++nt)
#pragma unroll
      for (int kc = 0; kc < 4; ++kc)
        bfr[s][nt][kc] = *(const bf16x8*)(wrb + s * 8192 +
                          ((((size_t)nt * 4 + kc) * 4 + quad) * 16 + l15) * 8);

  f32x4 acc[2];
#pragma unroll
  for (int b = 0; b < 2; ++b) {
    f32x4 z = {0.f, 0.f, 0.f, 0.f};
    acc[b] = z;
  }

  const float* xp = x + (size_t)(tokw + l15) * DIM + quad * 8;
  float4 va[4][2];
#pragma unroll
  for (int kc = 0; kc < 4; ++kc) {
    const float4* p = (const float4*)(xp + kc * 32);
    va[kc][0] = p[0];
    va[kc][1] = p[1];
  }
#pragma unroll
  for (int kc = 0; kc < 4; ++kc) {
    uint2 s0 = split2(va[kc][0].x, va[kc][0].y);
    uint2 s1 = split2(va[kc][0].z, va[kc][0].w);
    uint2 s2 = split2(va[kc][1].x, va[kc][1].y);
    uint2 s3 = split2(va[kc][1].z, va[kc][1].w);
    uint4v hu, lu;
    hu[0] = s0.x; lu[0] = s0.y;
    hu[1] = s1.x; lu[1] = s1.y;
    hu[2] = s2.x; lu[2] = s2.y;
    hu[3] = s3.x; lu[3] = s3.y;
    bf16x8 ahi = __builtin_bit_cast(bf16x8, hu);
    bf16x8 alo = __builtin_bit_cast(bf16x8, lu);
#pragma unroll
    for (int nt = 0; nt < 2; ++nt) {
      acc[nt] = __builtin_amdgcn_mfma_f32_16x16x32_bf16(ahi, bfr[0][nt][kc], acc[nt], 0, 0, 0);
      acc[nt] = __builtin_amdgcn_mfma_f32_16x16x32_bf16(ahi, bfr[1][nt][kc], acc[nt], 0, 0, 0);
      acc[nt] = __builtin_amdgcn_mfma_f32_16x16x32_bf16(alo, bfr[0][nt][kc], acc[nt], 0, 0, 0);
    }
  }

  float brv0 = br[l15], brv1 = br[16 + l15];
  const float NINF = -3.0e38f;
#pragma unroll
  for (int r = 0; r < 4; ++r) {
    float c0 = acc[0][r] + brv0;
    float c1 = acc[1][r] + brv1;
    float va2 = (c0 >= c1) ? c0 : c1;
    int ia = (c0 >= c1) ? l15 : 16 + l15;
#pragma unroll
    for (int off = 1; off < 16; off <<= 1) {
      float ov = __shfl_xor(va2, off);
      int oi = __shfl_xor(ia, off);
      if (ov > va2 || (ov == va2 && oi < ia)) { va2 = ov; ia = oi; }
    }
    float v1 = va2; int i1 = ia;
    float d0 = (i1 == l15) ? NINF : c0;
    float d1 = (i1 == 16 + l15) ? NINF : c1;
    float vb = (d0 >= d1) ? d0 : d1;
    int ib = (d0 >= d1) ? l15 : 16 + l15;
#pragma unroll
    for (int off = 1; off < 16; off <<= 1) {
      float ov = __shfl_xor(vb, off);
      int oi = __shfl_xor(ib, off);
      if (ov > vb || (ov == vb && oi < ib)) { vb = ov; ib = oi; }
    }
    float v2 = vb; int i2 = ib;
    float e0 = (i1 == l15 || i2 == l15) ? NINF : c0;
    float e1 = (i1 == 16 + l15 || i2 == 16 + l15) ? NINF : c1;
    float vc = (e0 >= e1) ? e0 : e1;
#pragma unroll
    for (int off = 1; off < 16; off <<= 1) {
      float ov = __shfl_xor(vc, off);
      vc = (ov > vc) ? ov : vc;
    }
    float s = __expf(c0 - v1) + __expf(c1 - v1);
#pragma unroll
    for (int off = 1; off < 16; off <<= 1) s += __shfl_xor(s, off);
    if (l15 == 0) {
      int n = tokw + quad * 4 + r;
      float g1 = 1.0f / s;
      float g2 = __expf(v2 - v1) / s;
      int2 ti; ti.x = i1; ti.y = i2;
      float2 tv; tv.x = g1; tv.y = g2;
      ((int2*)top_idx)[n] = ti;
      ((float2*)top_val)[n] = tv;
      atomicAdd(&hc[i1], 1);
      atomicAdd(&hc[i2], 1);
      atomicAdd(&hf[i1], g1);
      atomicAdd(&hf[i2], g2);
      if (v2 - vc < 2e-3f) {
        int sidx = atomicAdd(n_suspect, 1);
        suspects[sidx] = n;
      }
    }
  }
  __syncthreads();
  if (t < NE) {
    atomicAdd(&counts[t], hc[t]);
    atomicAdd(&importance[t], hf[t]);
  }
}

// ---------------- fp64 re-resolution of near-tie tokens (+ hist deltas) ----------------
__global__ __launch_bounds__(256) void k_router_fix(
    const float* __restrict__ x, const double* __restrict__ wrt64,
    const float* __restrict__ br, const int* __restrict__ suspects,
    const int* __restrict__ n_suspect, int* __restrict__ top_idx,
    float* __restrict__ top_val, int* __restrict__ counts,
    float* __restrict__ importance) {
  int t = threadIdx.x;
  int lt = t & 31;
  int gid = blockIdx.x * 8 + (t >> 5);
  int cnt = *n_suspect;
  const double* wcol = wrt64 + lt * DIM;
  for (int s = gid; s < cnt; s += 128 * 8) {
    int n = suspects[s];
    const float* xr = x + (size_t)n * DIM;
    double a = 0.0;
#pragma unroll 8
    for (int d = 0; d < DIM; ++d) a = fma((double)xr[d], wcol[d], a);
    double lv = a + (double)br[lt];

    double v1 = lv; int i1 = lt;
#pragma unroll
    for (int off = 16; off > 0; off >>= 1) {
      double ov = __shfl_xor(v1, off, 32);
      int oi = __shfl_xor(i1, off, 32);
      if (ov > v1 || (ov == v1 && oi < i1)) { v1 = ov; i1 = oi; }
    }
    double lv2 = (lt == i1) ? -1.0e300 : lv;
    double v2 = lv2; int i2 = lt;
#pragma unroll
    for (int off = 16; off > 0; off >>= 1) {
      double ov = __shfl_xor(v2, off, 32);
      int oi = __shfl_xor(i2, off, 32);
      if (ov > v2 || (ov == v2 && oi < i2)) { v2 = ov; i2 = oi; }
    }
    float p = expf((float)(lv - v1));
    float ssum = p;
#pragma unroll
    for (int off = 16; off > 0; off >>= 1) ssum += __shfl_xor(ssum, off, 32);
    if (lt == 0) {
      int i1o = top_idx[n * 2 + 0], i2o = top_idx[n * 2 + 1];
      float g1o = top_val[n * 2 + 0], g2o = top_val[n * 2 + 1];
      float g1 = 1.0f / ssum;
      float g2 = expf((float)(v2 - v1)) / ssum;
      top_idx[n * 2 + 0] = i1;
      top_idx[n * 2 + 1] = i2;
      top_val[n * 2 + 0] = g1;
      top_val[n * 2 + 1] = g2;
      atomicAdd(&counts[i1o], -1); atomicAdd(&counts[i2o], -1);
      atomicAdd(&counts[i1], 1);   atomicAdd(&counts[i2], 1);
      atomicAdd(&importance[i1o], -g1o); atomicAdd(&importance[i2o], -g2o);
      atomicAdd(&importance[i1], g1);    atomicAdd(&importance[i2], g2);
    }
  }
}

// ---------------- fallback-only: fp64 router ----------------
__global__ __launch_bounds__(256) void k_router_f64(const float* __restrict__ x,
                                                    const double* __restrict__ wrt64,
                                                    const float* __restrict__ br,
                                                    int* __restrict__ top_idx,
                                                    float* __restrict__ top_val) {
  int t = threadIdx.x;
  int lt = t & 31;
  int n = blockIdx.x * 8 + (t >> 5);
  const double* wcol = wrt64 + lt * DIM;
  const float* xr = x + (size_t)n * DIM;
  double a = 0.0;
#pragma unroll 8
  for (int d = 0; d < DIM; ++d) a = fma((double)xr[d], wcol[d], a);
  double lv = a + (double)br[lt];
  double v1 = lv; int i1 = lt;
#pragma unroll
  for (int off = 16; off > 0; off >>= 1) {
    double ov = __shfl_xor(v1, off, 32);
    int oi = __shfl_xor(i1, off, 32);
    if (ov > v1 || (ov == v1 && oi < i1)) { v1 = ov; i1 = oi; }
  }
  double lv2 = (lt == i1) ? -1.0e300 : lv;
  double v2 = lv2; int i2 = lt;
#pragma unroll
  for (int off = 16; off > 0; off >>= 1) {
    double ov = __shfl_xor(v2, off, 32);
    int oi = __shfl_xor(i2, off, 32);
    if (ov > v2 || (ov == v2 && oi < i2)) { v2 = ov; i2 = oi; }
  }
  float p = expf((float)(lv - v1));
  float ssum = p;
#pragma unroll
  for (int off = 16; off > 0; off >>= 1) ssum += __shfl_xor(ssum, off, 32);
  if (lt == 0) {
    top_idx[n * 2 + 0] = i1;
    top_idx[n * 2 + 1] = i2;
    top_val[n * 2 + 0] = 1.0f / ssum;
    top_val[n * 2 + 1] = expf((float)(v2 - v1)) / ssum;
  }
}

// ---------------- fallback-only: histogram ----------------
__global__ void k_hist(const int* __restrict__ top_idx, const float* __restrict__ top_val,
                       int* __restrict__ counts, float* __restrict__ importance) {
  __shared__ int hc[NE];
  __shared__ float hf[NE];
  int t = threadIdx.x;
  if (t < NE) { hc[t] = 0; hf[t] = 0.f; }
  __syncthreads();
#pragma unroll
  for (int j = 0; j < 2; ++j) {
    int i = (j * 256 + blockIdx.x) * 256 + t;
    int e = top_idx[i];
    atomicAdd(&hc[e], 1);
    atomicAdd(&hf[e], top_val[i]);
  }
  __syncthreads();
  if (t < NE) {
    atomicAdd(&counts[t], hc[t]);
    atomicAdd(&importance[t], hf[t]);
  }
}

// ---------------- scatter (+ in-block scan, block0 computes loss); 512 blocks ----------------
// perm[pos] = token*2 + k
__global__ void k_scatter(const int* __restrict__ top_idx, const float* __restrict__ top_val,
                          const int* __restrict__ counts, const float* __restrict__ importance,
                          int* __restrict__ cursors, int* __restrict__ perm,
                          float* __restrict__ gatev, float* __restrict__ out_loss) {
  __shared__ int hist[NE], base[NE], cur[NE], off_s[NE];
  int t = threadIdx.x;
  if (t < NE) {
    hist[t] = 0; cur[t] = 0;
    int pc = (counts[t] + 63) & ~63;
    int sc = pc;
#pragma unroll
    for (int off = 1; off < 32; off <<= 1) {
      int ov = __shfl_up(sc, off, 32);
      if (t >= off) sc += ov;
    }
    off_s[t] = sc - pc;
    if (blockIdx.x == 0) {
      float imp = importance[t];
      float ssum = imp;
#pragma unroll
      for (int off = 16; off > 0; off >>= 1) ssum += __shfl_xor(ssum, off, 32);
      float mean = ssum / 32.0f;
      float dlt = imp - mean;
      float v = dlt * dlt;
#pragma unroll
      for (int off = 16; off > 0; off >>= 1) v += __shfl_xor(v, off, 32);
      float var = v / 31.0f;
      if (t == 0) *out_loss = var / (mean * mean + 1e-9f);
    }
  }
  __syncthreads();
  int i = blockIdx.x * 256 + t;
  int e = top_idx[i];
  atomicAdd(&hist[e], 1);
  __syncthreads();
  if (t < NE) base[t] = atomicAdd(&cursors[t], hist[t]);
  __syncthreads();
  int p = atomicAdd(&cur[e], 1);
  int pos = off_s[e] + base[e] + p;
  perm[pos] = i;                 // token*2 + k
  gatev[pos] = top_val[i];
}

// ---------------- fused expert GEMM: 64 tokens x 1 expert per block (2080 blocks) ----------------
// Weights in VGPRs, column-permuted so H-writeback packs 4 adjacent h per lane (b64 LDS writes)
// and epilogue packs 2 adjacent d per lane (b32 global stores).
template <int YB>
__global__ __launch_bounds__(256, 2) void k_expert(
    const float* __restrict__ x, const unsigned short* __restrict__ w1t,
    const unsigned short* __restrict__ w2t, const float* __restrict__ b1,
    const float* __restrict__ b2, const int* __restrict__ counts,
    const int* __restrict__ perm, const float* __restrict__ gatev,
    unsigned short* __restrict__ ybuf, float* __restrict__ out) {
  __shared__ __align__(16) unsigned char smem[49152];
  unsigned char* xa = smem;                 // 16 KB: [c 0..15][row 0..63][16B]
  unsigned char* ha = smem + 16384;         // 32 KB: [c 0..31][row 0..63][16B]
  __shared__ int off_s[NE + 1];

  int t = threadIdx.x;
  if (t < NE) {
    int pc = (counts[t] + 63) & ~63;
    int sc = pc;
#pragma unroll
    for (int off = 1; off < 32; off <<= 1) {
      int ov = __shfl_up(sc, off, 32);
      if (t >= off) sc += ov;
    }
    off_s[t] = sc - pc;
    if (t == NE - 1) off_s[NE] = sc;
  }
  __syncthreads();

  int slot0 = blockIdx.x * 64;
  if (slot0 >= off_s[NE]) return;
  int e = 0;
#pragma unroll
  for (int i = 1; i < NE; ++i)
    if (slot0 >= off_s[i]) e = i;
  int cnt = counts[e];
  int local0 = slot0 - off_s[e];
  int nvalid = min(64, cnt - local0);

  int w = t >> 6;
  int l = t & 63;
  int quad = l >> 4;
  int l15 = l & 15;

  // ---- W1 fragments -> VGPRs ----
  const unsigned short* w1e = w1t + (size_t)e * DIM * HID;
  bf16x8 w1f[4][4];
#pragma unroll
  for (int kc = 0; kc < 4; ++kc)
#pragma unroll
    for (int jt = 0; jt < 4; ++jt)
      w1f[kc][jt] = *(const bf16x8*)(w1e + kc * 8192 + (w * 64 + jt * 16 + l15) * 32 + quad * 8);

  // ---- stage x rows into LDS (gather + fp32->bf16) ----
  {
    int r = t & 63;
    int half = t >> 6;
    unsigned pk[16];
    if (r < nvalid) {
      int pmv = perm[slot0 + r];
      const float* src = x + (size_t)(pmv >> 1) * DIM + half * 32;
#pragma unroll
      for (int q = 0; q < 8; ++q) {
        float4 v = ((const float4*)src)[q];
        pk[q * 2 + 0] = (unsigned)f2bf(v.x) | ((unsigned)f2bf(v.y) << 16);
        pk[q * 2 + 1] = (unsigned)f2bf(v.z) | ((unsigned)f2bf(v.w) << 16);
      }
    } else {
#pragma unroll
      for (int q = 0; q < 16; ++q) pk[q] = 0u;
    }
#pragma unroll
    for (int cc = 0; cc < 4; ++cc) {
      uint4 u;
      u.x = pk[cc * 4 + 0]; u.y = pk[cc * 4 + 1]; u.z = pk[cc * 4 + 2]; u.w = pk[cc * 4 + 3];
      *(uint4*)(xa + (half * 4 + cc) * 1024 + r * 16) = u;
    }
  }
  __syncthreads();

  // ---- stage 1: H = relu(X @ W1e + b1); tile jt holds cols w*64 + n*4 + jt ----
  f32x4 acc[4][4];
#pragma unroll
  for (int a = 0; a < 4; ++a)
#pragma unroll
    for (int b = 0; b < 4; ++b) {
      f32x4 z = {0.f, 0.f, 0.f, 0.f};
      acc[a][b] = z;
    }
#pragma unroll
  for (int kc = 0; kc < 4; ++kc) {
    bf16x8 af[4];
#pragma unroll
    for (int rt = 0; rt < 4; ++rt)
      af[rt] = *(const bf16x8*)(xa + (kc * 4 + quad) * 1024 + (rt * 16 + l15) * 16);
#pragma unroll
    for (int rt = 0; rt < 4; ++rt)
#pragma unroll
      for (int jt = 0; jt < 4; ++jt)
        acc[rt][jt] = __builtin_amdgcn_mfma_f32_16x16x32_bf16(af[rt], w1f[kc][jt], acc[rt][jt], 0, 0, 0);
  }

  // ---- W2 fragments -> VGPRs ----
  const unsigned short* w2e = w2t + (size_t)e * HID * DIM;
  bf16x8 w2f[8][2];
#pragma unroll
  for (int hc = 0; hc < 8; ++hc)
#pragma unroll
    for (int jt = 0; jt < 2; ++jt)
      w2f[hc][jt] = *(const bf16x8*)(w2e + hc * 4096 + (w * 32 + jt * 16 + l15) * 32 + quad * 8);

  // ---- bias + relu + H -> LDS, packed b64 (lane owns h0..h0+3, h0 = w*64+l15*4) ----
  {
    const float* b1e = b1 + e * HID;
    int h0 = w * 64 + l15 * 4;
    float b1v[4];
#pragma unroll
    for (int jt = 0; jt < 4; ++jt) b1v[jt] = b1e[h0 + jt];
    int cidx = h0 >> 3;
    int boff = (h0 & 7) * 2;
#pragma unroll
    for (int rt = 0; rt < 4; ++rt) {
#pragma unroll
      for (int r = 0; r < 4; ++r) {
        int token = rt * 16 + quad * 4 + r;
        float v0 = acc[rt][0][r] + b1v[0]; v0 = v0 > 0.f ? v0 : 0.f;
        float v1 = acc[rt][1][r] + b1v[1]; v1 = v1 > 0.f ? v1 : 0.f;
        float v2 = acc[rt][2][r] + b1v[2]; v2 = v2 > 0.f ? v2 : 0.f;
        float v3 = acc[rt][3][r] + b1v[3]; v3 = v3 > 0.f ? v3 : 0.f;
        uint2 u;
        u.x = (unsigned)f2bf(v0) | ((unsigned)f2bf(v1) << 16);
        u.y = (unsigned)f2bf(v2) | ((unsigned)f2bf(v3) << 16);
        *(uint2*)(ha + cidx * 1024 + token * 16 + boff) = u;
      }
    }
  }
  __syncthreads();

  // ---- stage 2: O = H @ W2e; tile jt holds cols dbase + n*2 + jt ----
  f32x4 accc[4][2];
#pragma unroll
  for (int a = 0; a < 4; ++a)
#pragma unroll
    for (int b = 0; b < 2; ++b) {
      f32x4 z = {0.f, 0.f, 0.f, 0.f};
      accc[a][b] = z;
    }
#pragma unroll
  for (int hc = 0; hc < 8; ++hc) {
    bf16x8 ah[4];
#pragma unroll
    for (int rt = 0; rt < 4; ++rt)
      ah[rt] = *(const bf16x8*)(ha + (hc * 4 + quad) * 1024 + (rt * 16 + l15) * 16);
#pragma unroll
    for (int rt = 0; rt < 4; ++rt)
#pragma unroll
      for (int jt = 0; jt < 2; ++jt)
        accc[rt][jt] = __builtin_amdgcn_mfma_f32_16x16x32_bf16(ah[rt], w2f[hc][jt], accc[rt][jt], 0, 0, 0);
  }

  // ---- epilogue: y = g*(O+b2), lane owns d pair {d0, d0+1}, d0 = w*32 + l15*2 ----
  int d0 = w * 32 + l15 * 2;
  float b2v0 = b2[e * DIM + d0];
  float b2v1 = b2[e * DIM + d0 + 1];
#pragma unroll
  for (int rt = 0; rt < 4; ++rt) {
#pragma unroll
    for (int rr = 0; rr < 4; ++rr) {
      int tokrow = rt * 16 + quad * 4 + rr;
      if (tokrow < nvalid) {
        int pos = slot0 + tokrow;
        int pmv = perm[pos];
        float g = gatev[pos];
        float y0 = g * (accc[rt][0][rr] + b2v0);
        float y1 = g * (accc[rt][1][rr] + b2v1);
        if (YB) {
          *(unsigned*)(ybuf + (size_t)pmv * DIM + d0) =
              (unsigned)f2bf(y0) | ((unsigned)f2bf(y1) << 16);
        } else {
          float* orow = out + (size_t)(pmv >> 1) * DIM;
          atomicAdd(&orow[d0], y0);
          atomicAdd(&orow[d0 + 1], y1);
        }
      }
    }
  }
}

// ---------------- combine: out[n] = ybuf[2n] + ybuf[2n+1] (fully coalesced) ----------------
__global__ __launch_bounds__(256) void k_combine(const unsigned short* __restrict__ ybuf,
                                                 float* __restrict__ out) {
  int t = threadIdx.x;
  int n = blockIdx.x * 16 + (t >> 4);
  int lane = t & 15;
  const uint4* rows = (const uint4*)(ybuf + (size_t)(2 * n) * DIM);
  uint4 a = rows[lane];
  uint4 b = rows[16 + lane];
  unsigned av[4] = {a.x, a.y, a.z, a.w}, bv[4] = {b.x, b.y, b.z, b.w};
  float r[8];
#pragma unroll
  for (int q = 0; q < 4; ++q) {
    r[q * 2 + 0] = bf2f(av[q] & 0xffffu) + bf2f(bv[q] & 0xffffu);
    r[q * 2 + 1] = bf2f(av[q] >> 16) + bf2f(bv[q] >> 16);
  }
  float* orow = out + (size_t)n * DIM + lane * 8;
  float4 w0 = {r[0], r[1], r[2], r[3]}, w1 = {r[4], r[5], r[6], r[7]};
  ((float4*)orow)[0] = w0;
  ((float4*)orow)[1] = w1;
}

extern "C" void kernel_launch(void* const* d_in, const int* in_sizes, int n_in,
                              void* d_out, int out_size, void* d_ws, size_t ws_size,
                              hipStream_t stream) {
  const float* x  = (const float*)d_in[0];
  const float* W1 = (const float*)d_in[1];
  const float* b1 = (const float*)d_in[2];
  const float* W2 = (const float*)d_in[3];
  const float* b2 = (const float*)d_in[4];
  const float* Wr = (const float*)d_in[5];
  const float* br = (const float*)d_in[6];
  float* out = (float*)d_out;

  char* ws = (char*)d_ws;
  float* importance   = (float*)(ws + 0);       // 32 f
  int*   counts       = (int*)(ws + 128);       // 32 i
  int*   cursors      = (int*)(ws + 256);       // 32 i
  int*   top_idx      = (int*)(ws + 1024);              // -> 525312
  float* top_val      = (float*)(ws + 525312);          // -> 1049600
  int*   perm         = (int*)(ws + 1049600);           // -> 1582080
  float* gatev        = (float*)(ws + 1582080);         // -> 2114560
  unsigned short* w1t = (unsigned short*)(ws + 2114560);            // 2 MB -> 4211712
  unsigned short* w2t = (unsigned short*)(ws + 4211712);            // 2 MB -> 6308864
  unsigned short* ybuf = (unsigned short*)(ws + 6308864);           // 32 MB -> 39863296
  double* wrt64 = (double*)(ws + 6308864);              // aliases ybuf head (dead before k_expert)
  unsigned short* wrb = (unsigned short*)(ws + 6308864 + 32768);    // aliases ybuf
  int* suspects = (int*)(ws + 39863296);                // -> 40125440
  int* n_suspect = (int*)(ws + 40125440);               // -> 40125568
  const size_t NEEDED = 40125568;
  bool use_ybuf = ws_size >= NEEDED;

  hipLaunchKernelGGL(k_weights, dim3(513), dim3(256), 0, stream, W1, W2, Wr, w1t, w2t, wrt64,
                     wrb, (float*)ws, n_suspect);
  if (use_ybuf) {
    hipLaunchKernelGGL(k_router, dim3(1024), dim3(256), 0, stream, x, wrb, br, top_idx, top_val,
                       suspects, n_suspect, counts, importance);
    hipLaunchKernelGGL(k_router_fix, dim3(128), dim3(256), 0, stream, x, wrt64, br, suspects,
                       n_suspect, top_idx, top_val, counts, importance);
  } else {
    hipLaunchKernelGGL(k_router_f64, dim3(8192), dim3(256), 0, stream, x, wrt64, br, top_idx,
                       top_val);
    hipLaunchKernelGGL(k_hist, dim3(256), dim3(256), 0, stream, top_idx, top_val, counts,
                       importance);
  }
  hipLaunchKernelGGL(k_scatter, dim3(512), dim3(256), 0, stream, top_idx, top_val, counts,
                     importance, cursors, perm, gatev, out + (size_t)N_TOK * DIM);
  if (use_ybuf) {
    hipLaunchKernelGGL((k_expert<1>), dim3(2080), dim3(256), 0, stream, x, w1t, w2t, b1, b2,
                       counts, perm, gatev, ybuf, out);
    hipLaunchKernelGGL(k_combine, dim3(4096), dim3(256), 0, stream, ybuf, out);
  } else {
    hipLaunchKernelGGL(k_zero_out, dim3(4096), dim3(256), 0, stream, out);
    hipLaunchKernelGGL((k_expert<0>), dim3(2080), dim3(256), 0, stream, x, w1t, w2t, b1, b2,
                       counts, perm, gatev, ybuf, out);
  }
}